// Round 2
// baseline (129.312 us; speedup 1.0000x reference)
//
#include <hip/hip_runtime.h>
#include <cmath>

#define BB 64
#define KK 100
#define QQ 100
#define CC 82
#define AA 118
#define KP1 101
#define AM1 117
#define SLAB (AM1 * KP1)      // 11817 elements per (b,h) slab
#define ROWSTRIDE (KK * KP1)  // 10100 floats between consecutive 'a' rows

// Kernel 1: per batch. Writes scores/labels/boxes to out, and per-query
// (h, o, coef) into workspace. coef = ms * (winner?2:1) * h_mask[h] * o_mask[o].
__global__ __launch_bounds__(128) void prep_kernel(
    const float* __restrict__ logits,   // B,K,C
    const float* __restrict__ boxes_in, // B,K,4
    const float* __restrict__ actions,  // B,Q,A
    const float* __restrict__ hidx,     // B,Q,K
    const float* __restrict__ oidx,     // B,Q,K
    const int*   __restrict__ tsizes,   // B,2
    float* __restrict__ out_scores,     // B,K
    float* __restrict__ out_labels,     // B,K
    float* __restrict__ out_boxes,      // B,K,4
    int*   __restrict__ wsh,            // B,Q
    int*   __restrict__ wso,            // B,Q
    float* __restrict__ wsc)            // B,Q
{
    int b = blockIdx.x;
    int tid = threadIdx.x;
    __shared__ float sh_score[KK];
    __shared__ float sh_label[KK];
    __shared__ int   sh_h[QQ];
    __shared__ int   sh_o[QQ];
    __shared__ float sh_ms[QQ];

    // Phase 1: softmax scores / labels / boxes for k = tid
    if (tid < KK) {
        const float* l = logits + ((size_t)b * KK + tid) * CC;
        float m = -INFINITY;
        for (int c = 0; c < CC; ++c) m = fmaxf(m, l[c]);
        float denom = 0.f, best = -INFINITY;
        int bi = 0;
        for (int c = 0; c < CC; ++c) {
            float v = l[c];
            denom += expf(v - m);
            if (c < CC - 1 && v > best) { best = v; bi = c; }
        }
        float score = expf(best - m) / denom;
        sh_score[tid] = score;
        sh_label[tid] = (float)bi;
        out_scores[b * KK + tid] = score;
        out_labels[b * KK + tid] = (float)bi;

        const float* bx = boxes_in + ((size_t)b * KK + tid) * 4;
        float cx = bx[0], cy = bx[1], w = bx[2], h = bx[3];
        float ih = (float)tsizes[b * 2 + 0];
        float iw = (float)tsizes[b * 2 + 1];
        float* ob = out_boxes + ((size_t)b * KK + tid) * 4;
        ob[0] = (cx - 0.5f * w) * iw;
        ob[1] = (cy - 0.5f * h) * ih;
        ob[2] = (cx + 0.5f * w) * iw;
        ob[3] = (cy + 0.5f * h) * ih;
    }

    // Phase 2: per-query argmax(hidx), argmax(oidx), ms
    if (tid < QQ) {
        const float* hp = hidx + ((size_t)b * QQ + tid) * KK;
        const float* op = oidx + ((size_t)b * QQ + tid) * KK;
        float bh = hp[0]; int ih = 0;
        float bo = op[0]; int io = 0;
        for (int k = 1; k < KK; ++k) {
            float v = hp[k]; if (v > bh) { bh = v; ih = k; }
            float w = op[k]; if (w > bo) { bo = w; io = k; }
        }
        sh_h[tid] = ih;
        sh_o[tid] = io;
        float x = actions[((size_t)b * QQ + tid) * AA + (AA - 1)];
        sh_ms[tid] = 1.f - 1.f / (1.f + expf(-x));
    }
    __syncthreads();

    // Phase 3: winner-per-segment + masks folded into coef
    if (tid < QQ) {
        int f = sh_h[tid] * KP1 + sh_o[tid];
        float myms = sh_ms[tid];
        bool winf = true;
        for (int q = 0; q < QQ; ++q) {
            if (sh_h[q] * KP1 + sh_o[q] == f) {
                float m2 = sh_ms[q];
                if (m2 > myms || (m2 == myms && q < tid)) { winf = false; break; }
            }
        }
        int hh = sh_h[tid], oo = sh_o[tid];
        float hm = (sh_label[hh] == 1.0f && sh_score[hh] > 0.0f) ? 1.f : 0.f;
        float om = (sh_score[oo] > 0.0f) ? 1.f : 0.f;
        wsh[b * QQ + tid] = hh;
        wso[b * QQ + tid] = oo;
        wsc[b * QQ + tid] = myms * (winf ? 2.f : 1.f) * hm * om;
    }
}

// Kernel 2: one block per (b,h). Writes the full 117x101 slab in one pass:
// 0 for columns with no matching query, sum of coef*sigmoid(act) otherwise.
__global__ __launch_bounds__(256) void pair_write_kernel(
    const float* __restrict__ actions, // B,Q,A
    const int*   __restrict__ wsh,
    const int*   __restrict__ wso,
    const float* __restrict__ wsc,
    float* __restrict__ out_pair)      // B,117,100,101
{
    int blk = blockIdx.x;
    int b = blk / KK;
    int h = blk - b * KK;
    int tid = threadIdx.x;
    int lane = tid & 63;
    int wave = tid >> 6;

    __shared__ int   mq[QQ];
    __shared__ int   moo[QQ];
    __shared__ float mcc[QQ];
    __shared__ unsigned omask[4];
    __shared__ int wcnt[4];

    if (tid < 4) omask[tid] = 0;

    // Gather matching queries deterministically (ballot compaction).
    bool flag = false;
    int o_m = 0; float c_m = 0.f;
    if (tid < QQ) {
        if (wsh[b * QQ + tid] == h) {
            c_m = wsc[b * QQ + tid];
            if (c_m != 0.f) { flag = true; o_m = wso[b * QQ + tid]; }
        }
    }
    unsigned long long bal = __ballot(flag);
    if (lane == 0) wcnt[wave] = __popcll(bal);
    __syncthreads();  // omask zeros + wcnt visible

    int base = 0;
    for (int w = 0; w < wave; ++w) base += wcnt[w];
    if (flag) {
        int pos = base + __popcll(bal & ((1ull << lane) - 1ull));
        mq[pos] = tid;
        moo[pos] = o_m;
        mcc[pos] = c_m;
        atomicOr(&omask[o_m >> 5], 1u << (o_m & 31));
    }
    __syncthreads();

    unsigned m0 = omask[0], m1 = omask[1], m2 = omask[2], m3 = omask[3];
    int n = wcnt[0] + wcnt[1] + wcnt[2] + wcnt[3];

    float* slab = out_pair + (size_t)b * AM1 * ROWSTRIDE + (size_t)h * KP1;
    int a = tid / KP1;
    int o = tid - a * KP1;
    for (int e = tid; e < SLAB; e += 256) {
        float v = 0.f;
        if (n) {
            unsigned mm = (o < 32) ? m0 : (o < 64) ? m1 : (o < 96) ? m2 : m3;
            if ((mm >> (o & 31)) & 1u) {
                for (int j = 0; j < n; ++j) {
                    if (moo[j] == o) {
                        float x = actions[((size_t)b * QQ + mq[j]) * AA + a];
                        v += mcc[j] / (1.f + expf(-x));
                    }
                }
            }
        }
        slab[(size_t)a * ROWSTRIDE + o] = v;
        // advance flat index by 256: a += 2, o += 54, normalize
        o += 256 - 2 * KP1;
        a += 2;
        if (o >= KP1) { o -= KP1; ++a; }
    }
}

extern "C" void kernel_launch(void* const* d_in, const int* in_sizes, int n_in,
                              void* d_out, int out_size, void* d_ws, size_t ws_size,
                              hipStream_t stream) {
    const float* pred_logits  = (const float*)d_in[0];
    const float* pred_boxes   = (const float*)d_in[1];
    const float* pred_actions = (const float*)d_in[2];
    const float* pred_hidx    = (const float*)d_in[3];
    const float* pred_oidx    = (const float*)d_in[4];
    const int*   target_sizes = (const int*)d_in[5];

    float* out = (float*)d_out;
    float* out_scores = out;                // B*K
    float* out_labels = out + BB * KK;      // B*K
    float* out_boxes  = out + 2 * BB * KK;  // B*K*4
    float* out_pair   = out + 6 * BB * KK;  // B*117*100*101

    int*   wsh = (int*)d_ws;
    int*   wso = wsh + BB * QQ;
    float* wsc = (float*)(wso + BB * QQ);

    prep_kernel<<<BB, 128, 0, stream>>>(pred_logits, pred_boxes, pred_actions,
                                        pred_hidx, pred_oidx, target_sizes,
                                        out_scores, out_labels, out_boxes,
                                        wsh, wso, wsc);

    pair_write_kernel<<<BB * KK, 256, 0, stream>>>(pred_actions, wsh, wso, wsc,
                                                   out_pair);
}

// Round 3
// 73.587 us; speedup vs baseline: 1.7573x; 1.7573x over previous
//
#include <hip/hip_runtime.h>
#include <cmath>

#define BB 64
#define KK 100
#define QQ 100
#define CC 82
#define AA 118
#define KP1 101
#define AM1 117
#define ROWSTRIDE (KK * KP1)  // 10100 floats: one [h][o] row for fixed (b,a)

// Kernel 1: one block per batch, 512 threads, wave-partitioned tasks.
// Writes scores/labels/boxes to out, and per-query (h, o, coef) to workspace.
// coef = ms * (winner?2:1) * h_mask[h] * o_mask[o].
__global__ __launch_bounds__(512) void prep_kernel(
    const float* __restrict__ logits,   // B,K,C
    const float* __restrict__ boxes_in, // B,K,4
    const float* __restrict__ actions,  // B,Q,A
    const float* __restrict__ hidx,     // B,Q,K
    const float* __restrict__ oidx,     // B,Q,K
    const int*   __restrict__ tsizes,   // B,2
    float* __restrict__ out_scores,     // B,K
    float* __restrict__ out_labels,     // B,K
    float* __restrict__ out_boxes,      // B,K,4
    int*   __restrict__ wsh,            // B,Q
    int*   __restrict__ wso,            // B,Q
    float* __restrict__ wsc)            // B,Q
{
    int b = blockIdx.x;
    int tid = threadIdx.x;
    __shared__ float sh_score[KK];
    __shared__ float sh_label[KK];
    __shared__ int   sh_h[QQ];
    __shared__ int   sh_o[QQ];
    __shared__ float sh_ms[QQ];

    if (tid < KK) {
        // waves 0-1: softmax scores/labels + boxes for k = tid
        const float2* l2 = (const float2*)(logits + ((size_t)b * KK + tid) * CC);
        float v[CC];
        #pragma unroll
        for (int i = 0; i < CC / 2; ++i) {
            float2 p = l2[i];
            v[2 * i] = p.x; v[2 * i + 1] = p.y;
        }
        float m = -INFINITY;
        #pragma unroll
        for (int c = 0; c < CC; ++c) m = fmaxf(m, v[c]);
        float denom = 0.f, best = -INFINITY;
        int bi = 0;
        #pragma unroll
        for (int c = 0; c < CC; ++c) {
            denom += expf(v[c] - m);
            if (c < CC - 1 && v[c] > best) { best = v[c]; bi = c; }
        }
        float score = expf(best - m) / denom;
        sh_score[tid] = score;
        sh_label[tid] = (float)bi;
        out_scores[b * KK + tid] = score;
        out_labels[b * KK + tid] = (float)bi;

        const float4 bx = *(const float4*)(boxes_in + ((size_t)b * KK + tid) * 4);
        float ih = (float)tsizes[b * 2 + 0];
        float iw = (float)tsizes[b * 2 + 1];
        float4 ob;
        ob.x = (bx.x - 0.5f * bx.z) * iw;
        ob.y = (bx.y - 0.5f * bx.w) * ih;
        ob.z = (bx.x + 0.5f * bx.z) * iw;
        ob.w = (bx.y + 0.5f * bx.w) * ih;
        *(float4*)(out_boxes + ((size_t)b * KK + tid) * 4) = ob;
    } else if (tid >= 128 && tid < 128 + QQ) {
        // waves 2-3: argmax over hidx for query q
        int q = tid - 128;
        const float4* rp = (const float4*)(hidx + ((size_t)b * QQ + q) * KK);
        float best = -INFINITY; int bi = 0;
        #pragma unroll
        for (int i = 0; i < KK / 4; ++i) {
            float4 r = rp[i];
            if (r.x > best) { best = r.x; bi = 4 * i; }
            if (r.y > best) { best = r.y; bi = 4 * i + 1; }
            if (r.z > best) { best = r.z; bi = 4 * i + 2; }
            if (r.w > best) { best = r.w; bi = 4 * i + 3; }
        }
        sh_h[q] = bi;
    } else if (tid >= 256 && tid < 256 + QQ) {
        // waves 4-5: argmax over oidx for query q
        int q = tid - 256;
        const float4* rp = (const float4*)(oidx + ((size_t)b * QQ + q) * KK);
        float best = -INFINITY; int bi = 0;
        #pragma unroll
        for (int i = 0; i < KK / 4; ++i) {
            float4 r = rp[i];
            if (r.x > best) { best = r.x; bi = 4 * i; }
            if (r.y > best) { best = r.y; bi = 4 * i + 1; }
            if (r.z > best) { best = r.z; bi = 4 * i + 2; }
            if (r.w > best) { best = r.w; bi = 4 * i + 3; }
        }
        sh_o[q] = bi;
    } else if (tid >= 384 && tid < 384 + QQ) {
        // waves 6-7: ms = 1 - sigmoid(last action)
        int q = tid - 384;
        float x = actions[((size_t)b * QQ + q) * AA + (AA - 1)];
        sh_ms[q] = 1.f - 1.f / (1.f + expf(-x));
    }
    __syncthreads();

    if (tid < QQ) {
        int f = sh_h[tid] * KP1 + sh_o[tid];
        float myms = sh_ms[tid];
        bool winf = true;
        for (int q = 0; q < QQ; ++q) {
            if (sh_h[q] * KP1 + sh_o[q] == f) {
                float m2 = sh_ms[q];
                if (m2 > myms || (m2 == myms && q < tid)) { winf = false; break; }
            }
        }
        int hh = sh_h[tid], oo = sh_o[tid];
        float hm = (sh_label[hh] == 1.0f && sh_score[hh] > 0.0f) ? 1.f : 0.f;
        float om = (sh_score[oo] > 0.0f) ? 1.f : 0.f;
        wsh[b * QQ + tid] = hh;
        wso[b * QQ + tid] = oo;
        wsc[b * QQ + tid] = myms * (winf ? 2.f : 1.f) * hm * om;
    }
}

// Kernel 2: one block per (b,a). Owns a CONTIGUOUS 10100-float row of
// out_pair: streams float4 zeros (fully coalesced, adjacent blocks adjacent
// in memory), then atomicAdd fixup of the <=100 matched cells (lines are
// L2-resident from the just-completed zero pass).
__global__ __launch_bounds__(256) void pair_write_kernel(
    const float* __restrict__ actions, // B,Q,A
    const int*   __restrict__ wsh,
    const int*   __restrict__ wso,
    const float* __restrict__ wsc,
    float* __restrict__ out_pair)      // B,117,100,101
{
    int blk = blockIdx.x;
    int b = blk / AM1;
    int a = blk - b * AM1;
    int tid = threadIdx.x;

    bool flag = false;
    int f = 0;
    float val = 0.f;
    if (tid < QQ) {
        float c = wsc[b * QQ + tid];
        if (c != 0.f) {
            flag = true;
            f = wsh[b * QQ + tid] * KP1 + wso[b * QQ + tid];
            float x = actions[((size_t)b * QQ + tid) * AA + a];
            val = c / (1.f + expf(-x));
        }
    }

    float* row = out_pair + ((size_t)b * AM1 + a) * ROWSTRIDE;
    float4* row4 = (float4*)row;
    const float4 z = make_float4(0.f, 0.f, 0.f, 0.f);
    #pragma unroll 2
    for (int i = tid; i < ROWSTRIDE / 4; i += 256) row4[i] = z;
    __syncthreads();

    if (flag) atomicAdd(row + f, val);
}

extern "C" void kernel_launch(void* const* d_in, const int* in_sizes, int n_in,
                              void* d_out, int out_size, void* d_ws, size_t ws_size,
                              hipStream_t stream) {
    const float* pred_logits  = (const float*)d_in[0];
    const float* pred_boxes   = (const float*)d_in[1];
    const float* pred_actions = (const float*)d_in[2];
    const float* pred_hidx    = (const float*)d_in[3];
    const float* pred_oidx    = (const float*)d_in[4];
    const int*   target_sizes = (const int*)d_in[5];

    float* out = (float*)d_out;
    float* out_scores = out;                // B*K
    float* out_labels = out + BB * KK;      // B*K
    float* out_boxes  = out + 2 * BB * KK;  // B*K*4
    float* out_pair   = out + 6 * BB * KK;  // B*117*100*101

    int*   wsh = (int*)d_ws;
    int*   wso = wsh + BB * QQ;
    float* wsc = (float*)(wso + BB * QQ);

    prep_kernel<<<BB, 512, 0, stream>>>(pred_logits, pred_boxes, pred_actions,
                                        pred_hidx, pred_oidx, target_sizes,
                                        out_scores, out_labels, out_boxes,
                                        wsh, wso, wsc);

    pair_write_kernel<<<BB * AM1, 256, 0, stream>>>(pred_actions, wsh, wso, wsc,
                                                    out_pair);
}